// Round 17
// baseline (213.298 us; speedup 1.0000x reference)
//
#include <hip/hip_runtime.h>
#include <cstdint>
#include <cstddef>

// Transformer block, B=2 S=2048 D=1024 H=16 DH=64 DFF=4096.
// Round 17: FF2 -> split-K-2 with 128x128/4-wave phase-interleaved pipeline
// (wave tile 64x64, LDS-read:MFMA 0.5; 512 blocks = 2/CU fixes r14's TLP).
// bf16 partials to dead ws regions + reduce kernel (p0+p1+bias+res).
// Everything else = r16 (204.5us best).

#define DEV static __device__ __forceinline__

typedef unsigned short u16;
typedef __bf16 bf16x8 __attribute__((ext_vector_type(8)));
typedef u16    u16x8  __attribute__((ext_vector_type(8)));
typedef u16    u16x4  __attribute__((ext_vector_type(4)));
typedef float  f32x4  __attribute__((ext_vector_type(4)));

#define AEXP2(x) __builtin_amdgcn_exp2f(x)

DEV u16 f2bfh(float f) {             // native RNE convert (1 VALU op)
  return __builtin_bit_cast(u16, (__bf16)f);
}
DEV float bf2f(u16 u) {
  return __builtin_bit_cast(float, (unsigned)u << 16);
}

// async global->LDS, 16B per lane. LDS dest must be linear in lane order.
DEV void gl16(const void* g, void* l) {
  __builtin_amdgcn_global_load_lds(
      (const __attribute__((address_space(1))) unsigned*)g,
      (__attribute__((address_space(3))) unsigned*)l, 16, 0, 0);
}

// ---------------------------------------------------------------------------
// ALL weight transposes (+fp32->bf16) in one dispatch. 12288 blocks.
// ---------------------------------------------------------------------------
__global__ __launch_bounds__(256)
void tconv_all(const float* __restrict__ w0, const float* __restrict__ w1,
               const float* __restrict__ w2, const float* __restrict__ w3,
               const float* __restrict__ W1, const float* __restrict__ W2,
               u16* __restrict__ q0, u16* __restrict__ q1,
               u16* __restrict__ q2, u16* __restrict__ q3,
               u16* __restrict__ W1t, u16* __restrict__ W2t)
{
  __shared__ float tile[32][33];
  const int bid = blockIdx.x;
  const float* in; u16* out; int R, C, r0, c0;
  if (bid < 4096) {
    const int z = bid >> 10, l = bid & 1023;
    in = z == 0 ? w0 : z == 1 ? w1 : z == 2 ? w2 : w3;
    out = z == 0 ? q0 : z == 1 ? q1 : z == 2 ? q2 : q3;
    R = 1024; C = 1024; r0 = (l >> 5) * 32; c0 = (l & 31) * 32;
  } else if (bid < 8192) {
    const int l = bid - 4096;
    in = W1; out = W1t; R = 1024; C = 4096;
    r0 = (l >> 7) * 32; c0 = (l & 127) * 32;
  } else {
    const int l = bid - 8192;
    in = W2; out = W2t; R = 4096; C = 1024;
    r0 = (l >> 5) * 32; c0 = (l & 31) * 32;
  }
  const int tx = threadIdx.x & 31, ty = threadIdx.x >> 5;   // 32 x 8
#pragma unroll
  for (int i = 0; i < 4; ++i)
    tile[ty + 8*i][tx] = in[(size_t)(r0 + ty + 8*i) * C + c0 + tx];
  __syncthreads();
#pragma unroll
  for (int i = 0; i < 4; ++i)
    out[(size_t)(c0 + ty + 8*i) * R + r0 + tx] = f2bfh(tile[tx][ty + 8*i]);
}

// ---------------------------------------------------------------------------
// LayerNorm over D=1024, one block (256 threads) per row, out bf16
// ---------------------------------------------------------------------------
__global__ __launch_bounds__(256)
void ln_fwd(const float* __restrict__ x, const float* __restrict__ g,
            const float* __restrict__ b, u16* __restrict__ out)
{
  const int row = blockIdx.x, t = threadIdx.x;
  const float4 v = ((const float4*)(x + (size_t)row * 1024))[t];
  float s1 = v.x + v.y + v.z + v.w;
  float s2 = v.x*v.x + v.y*v.y + v.z*v.z + v.w*v.w;
#pragma unroll
  for (int d = 1; d < 64; d <<= 1) {
    s1 += __shfl_xor(s1, d, 64);
    s2 += __shfl_xor(s2, d, 64);
  }
  __shared__ float sh[8];
  const int w = t >> 6;
  if ((t & 63) == 0) { sh[w] = s1; sh[w + 4] = s2; }
  __syncthreads();
  s1 = sh[0] + sh[1] + sh[2] + sh[3];
  s2 = sh[4] + sh[5] + sh[6] + sh[7];
  const float mu  = s1 * (1.0f / 1024.0f);
  const float var = s2 * (1.0f / 1024.0f) - mu * mu;
  const float rs  = rsqrtf(var + 1e-5f);
  const float4 gv = ((const float4*)g)[t];
  const float4 bv = ((const float4*)b)[t];
  u16x4 o;
  o[0] = f2bfh((v.x - mu) * rs * gv.x + bv.x);
  o[1] = f2bfh((v.y - mu) * rs * gv.y + bv.y);
  o[2] = f2bfh((v.z - mu) * rs * gv.z + bv.z);
  o[3] = f2bfh((v.w - mu) * rs * gv.w + bv.w);
  *(u16x4*)(out + (size_t)row * 1024 + t * 4) = o;
}

#define EPI_QKV  0
#define EPI_RES  1
#define EPI_GELU 2

#define QSCALE 0.180421f   // 0.125 * log2(e): softmax runs in exp2 domain

// paired-row LDS layout helper (32-col tiles):
// byte(R,kc) = (R>>1)*128 + (R&1)*64 + ((kc ^ ((R>>1)&3))<<4)
DEV int ldsoff(int R, int kc) {
  return (R >> 1) * 128 + (R & 1) * 64 + ((kc ^ ((R >> 1) & 3)) << 4);
}

// ---------------------------------------------------------------------------
// 256x256 GEMM (QKV/FF1), 8 waves (2Mx4N, 128x64/wave), BK=32, 3-buffer
// depth-2 phase-interleaved pipeline, counted vmcnt(4), paired-row LDS.
// ---------------------------------------------------------------------------
template<int EPI>
__global__ __launch_bounds__(512, 2)
void gemm256(const u16* __restrict__ A, const u16* __restrict__ Bt,
             const float* __restrict__ b0, const float* __restrict__ b1,
             const float* __restrict__ b2,
             u16* __restrict__ o0, u16* __restrict__ o1, u16* __restrict__ o2,
             int N, int K)
{
  __shared__ u16 As[3][8192];   // 16KB each: 256 rows x 32 cols, paired-row
  __shared__ u16 Bs[3][8192];
  const int t = threadIdx.x, lane = t & 63, w = t >> 6;
  const int wr = w >> 2, wc = w & 3;
  const int d = blockIdx.x + gridDim.x * blockIdx.y;
  const int rr = d >> 3;
  const int m0 = ((d & 7) * 2 + (rr & 1)) * 256;
  const int n0 = (rr >> 1) * 256;
  const int li = lane & 15, lg = lane >> 4;

  const int srow = t >> 2;                       // 0..127
  const int skc  = (t & 3) ^ ((t >> 3) & 3);
  const u16* Ag = A  + (size_t)(m0 + srow) * K + skc * 8;
  const u16* Bg = Bt + (size_t)(n0 + srow) * K + skc * 8;

  auto STG_A = [&](int k0, int b) {
#pragma unroll
    for (int p = 0; p < 2; ++p)
      gl16(Ag + k0 + (size_t)(p * 128) * K, &As[b][t * 8 + p * 4096]);
  };
  auto STG_B = [&](int k0, int b) {
#pragma unroll
    for (int p = 0; p < 2; ++p)
      gl16(Bg + k0 + (size_t)(p * 128) * K, &Bs[b][t * 8 + p * 4096]);
  };

  f32x4 acc[8][4] = {};
  const int NT = K >> 5;

  STG_A(0, 0);  STG_B(0, 0);
  STG_A(32, 1); STG_B(32, 1);

  int cur = 0, nxt = 2;
  for (int kt = 0; kt < NT; ++kt) {
    if (kt + 1 < NT)
      asm volatile("s_waitcnt vmcnt(4)" ::: "memory");
    else
      asm volatile("s_waitcnt vmcnt(0)" ::: "memory");
    __builtin_amdgcn_s_barrier();
    __builtin_amdgcn_sched_barrier(0);

    const int k2 = (kt + 2) * 32;
    bf16x8 bfr[4], afA[4];
#pragma unroll
    for (int i = 0; i < 4; ++i)
      bfr[i] = *(const bf16x8*)((const char*)Bs[cur] +
                                ldsoff(wc * 64 + i * 16 + li, lg));
#pragma unroll
    for (int i = 0; i < 4; ++i)
      afA[i] = *(const bf16x8*)((const char*)As[cur] +
                                ldsoff(wr * 128 + i * 16 + li, lg));
    if (kt + 2 < NT) STG_A(k2, nxt);
    __builtin_amdgcn_s_setprio(1);
#pragma unroll
    for (int mi = 0; mi < 4; ++mi)
#pragma unroll
      for (int ni = 0; ni < 4; ++ni)
        acc[mi][ni] = __builtin_amdgcn_mfma_f32_16x16x32_bf16(
            afA[mi], bfr[ni], acc[mi][ni], 0, 0, 0);
    __builtin_amdgcn_s_setprio(0);

    bf16x8 afB[4];
#pragma unroll
    for (int i = 0; i < 4; ++i)
      afB[i] = *(const bf16x8*)((const char*)As[cur] +
                                ldsoff(wr * 128 + (4 + i) * 16 + li, lg));
    if (kt + 2 < NT) STG_B(k2, nxt);
    __builtin_amdgcn_s_setprio(1);
#pragma unroll
    for (int mi = 0; mi < 4; ++mi)
#pragma unroll
      for (int ni = 0; ni < 4; ++ni)
        acc[4 + mi][ni] = __builtin_amdgcn_mfma_f32_16x16x32_bf16(
            afB[mi], bfr[ni], acc[4 + mi][ni], 0, 0, 0);
    __builtin_amdgcn_s_setprio(0);

    cur = (cur + 1 == 3) ? 0 : cur + 1;
    nxt = (nxt + 1 == 3) ? 0 : nxt + 1;
  }

  const int crow = wr * 128 + lg * 4;
  const int ccol = wc * 64 + li;

  if (EPI == EPI_QKV) {
    const int which = n0 >> 10;                     // 0=q 1=k 2=v (uniform)
    const float* bias = which == 0 ? b0 : which == 1 ? b1 : b2;
    const int nn0 = n0 & 1023;
    if (which == 2) {
      // V: write transposed [BH][64][2048]; r -> consecutive s => u16x4 store
#pragma unroll
      for (int mi = 0; mi < 8; ++mi)
#pragma unroll
        for (int ni = 0; ni < 4; ++ni) {
          const int gm0 = m0 + crow + mi * 16;
          const int b_ = gm0 >> 11, s_ = gm0 & 2047;
          const int gc = nn0 + ccol + ni * 16;
          const int h_ = gc >> 6, d_ = gc & 63;
          u16x4 pk;
#pragma unroll
          for (int r = 0; r < 4; ++r) pk[r] = f2bfh(acc[mi][ni][r] + bias[gc]);
          *(u16x4*)(o2 + ((size_t)(b_ * 16 + h_) * 64 + d_) * 2048 + s_) = pk;
        }
    } else {
      u16* outp = which == 0 ? o0 : o1;
      const float sc = which == 0 ? QSCALE : 1.0f;
#pragma unroll
      for (int mi = 0; mi < 8; ++mi)
#pragma unroll
        for (int ni = 0; ni < 4; ++ni)
#pragma unroll
          for (int r = 0; r < 4; ++r) {
            const int gm = m0 + crow + mi * 16 + r;
            const int gc = nn0 + ccol + ni * 16;
            const float v = (acc[mi][ni][r] + bias[gc]) * sc;
            const int b_ = gm >> 11, s_ = gm & 2047;
            const int h_ = gc >> 6,  d_ = gc & 63;
            outp[((size_t)(b_ * 16 + h_) * 2048 + s_) * 64 + d_] = f2bfh(v);
          }
    }
  } else {
#pragma unroll
    for (int mi = 0; mi < 8; ++mi)
#pragma unroll
      for (int ni = 0; ni < 4; ++ni)
#pragma unroll
        for (int r = 0; r < 4; ++r) {
          const int gm = m0 + crow + mi * 16 + r;
          const int gn = n0 + ccol + ni * 16;
          const float v = acc[mi][ni][r] + b0[gn];
          const float y = 0.7978845608f * (v + 0.044715f * v * v * v);
          const float e = AEXP2(fminf(y * 2.8853900818f, 80.0f));
          const float gl = v * e * __builtin_amdgcn_rcpf(e + 1.0f);
          o0[(size_t)gm * N + gn] = f2bfh(gl);
        }
  }
}

// ---------------------------------------------------------------------------
// Skinny GEMM (Wo): BM=64 x 128, 4 waves, BK=64, 3-buffer depth-2
// pipeline with counted vmcnt(6). XCD swizzle CM=8.
// out fp32 = acc + bias + res.
// ---------------------------------------------------------------------------
template<int EPI, int BM, int CM>
__global__ __launch_bounds__(256)
void gemm_bt(const u16* __restrict__ A, const u16* __restrict__ Bt,
             const float* __restrict__ b0, const float* __restrict__ res,
             float* __restrict__ outf, u16* __restrict__ o0,
             int N, int K)
{
  constexpr int MI = BM / 32;
  constexpr int RA = BM / 32;
  static_assert(BM == 64, "vmcnt(6) assumes 6 loads/step");
  __shared__ u16 As[3][BM * 64];
  __shared__ u16 Bs[3][128 * 64];
  const int t = threadIdx.x, lane = t & 63, w = t >> 6;
  const int wr = w >> 1, wc = w & 1;
  const int d = blockIdx.x + gridDim.x * blockIdx.y;
  const int rr = d >> 3;
  const int m0 = ((d & 7) * CM + rr % CM) * BM;
  const int n0 = (rr / CM) * 128;
  const int li = lane & 15, lg = lane >> 4;

  const int srow = t >> 3;
  const int schunk = (t & 7) ^ (srow & 7);
  const u16* Ag = A  + (size_t)(m0 + srow) * K + schunk * 8;
  const u16* Bg = Bt + (size_t)(n0 + srow) * K + schunk * 8;

  auto STG = [&](int k0, int b) {
#pragma unroll
    for (int p = 0; p < RA; ++p)
      gl16(Ag + k0 + (size_t)(p * 32) * K, &As[b][t * 8 + p * 2048]);
#pragma unroll
    for (int p = 0; p < 4; ++p)
      gl16(Bg + k0 + (size_t)(p * 32) * K, &Bs[b][t * 8 + p * 2048]);
  };

  f32x4 acc[MI][4] = {};
  const int swz = (li & 7) << 4;

  auto COMPUTE = [&](int cur) {
#pragma unroll
    for (int ks = 0; ks < 2; ++ks) {
      bf16x8 af[MI], bfr[4];
#pragma unroll
      for (int i = 0; i < MI; ++i) {
        const int Ra = wr * (MI * 16) + i * 16 + li;
        af[i] = *(const bf16x8*)((const char*)As[cur] + Ra * 128 +
                                 ((ks * 64 + lg * 16) ^ swz));
      }
#pragma unroll
      for (int i = 0; i < 4; ++i) {
        const int Rb = wc * 64 + i * 16 + li;
        bfr[i] = *(const bf16x8*)((const char*)Bs[cur] + Rb * 128 +
                                  ((ks * 64 + lg * 16) ^ swz));
      }
#pragma unroll
      for (int mi = 0; mi < MI; ++mi)
#pragma unroll
        for (int ni = 0; ni < 4; ++ni)
          acc[mi][ni] = __builtin_amdgcn_mfma_f32_16x16x32_bf16(
              af[mi], bfr[ni], acc[mi][ni], 0, 0, 0);
    }
  };

  STG(0, 0);
  if (64 < K) STG(64, 1);
  int cur = 0;
  for (int k0 = 0; k0 < K; k0 += 64) {
    if (k0 + 64 < K)
      asm volatile("s_waitcnt vmcnt(6)" ::: "memory");
    else
      asm volatile("s_waitcnt vmcnt(0)" ::: "memory");
    __builtin_amdgcn_s_barrier();
    __builtin_amdgcn_sched_barrier(0);
    COMPUTE(cur);
    if (k0 + 128 < K) {
      int nxt = cur + 2; if (nxt >= 3) nxt -= 3;
      STG(k0 + 128, nxt);
    }
    cur = (cur + 1 == 3) ? 0 : cur + 1;
  }

  const int crow = wr * (MI * 16) + lg * 4;
  const int ccol = wc * 64 + li;
#pragma unroll
  for (int mi = 0; mi < MI; ++mi)
#pragma unroll
    for (int ni = 0; ni < 4; ++ni)
#pragma unroll
      for (int r = 0; r < 4; ++r) {
        const int gm = m0 + crow + mi * 16 + r;
        const int gn = n0 + ccol + ni * 16;
        const float v = acc[mi][ni][r] + b0[gn];
        const size_t o = (size_t)gm * N + gn;
        outf[o] = v + res[o];
      }
}

// ---------------------------------------------------------------------------
// FF2 split-K GEMM: 128x128 tile, 4 waves of 64x64, BK=32, 3-buffer depth-2
// phase-interleaved pipeline (r14-verified), K split in 2 halves (kz).
// Grid 512 = 2 blocks/CU. XCD owns m-rows [x*512,(x+1)*512) for both kz.
// Writes bf16 partial (no bias/res; reduce adds them).
// ---------------------------------------------------------------------------
__global__ __launch_bounds__(256)
void gemm128sk(const u16* __restrict__ A, const u16* __restrict__ Bt,
               u16* __restrict__ p0, u16* __restrict__ p1, int N, int K2)
{
  __shared__ u16 As[3][4096];   // 8KB each: 128 rows x 32 cols, paired-row
  __shared__ u16 Bs[3][4096];
  const int t = threadIdx.x, lane = t & 63, w = t >> 6;
  const int wr = w >> 1, wc = w & 1;
  const int d = blockIdx.x;                 // 0..511
  const int x = d & 7;                      // XCD
  const int q = d >> 3;                     // 0..63
  const int kz = q & 1;
  const int rr = q >> 1;                    // 0..31
  const int m0 = x * 512 + (rr & 3) * 128;
  const int n0 = (rr >> 2) * 128;
  const int kb = kz * K2;
  const int li = lane & 15, lg = lane >> 4;
  u16* outp = kz ? p1 : p0;

  const int srow = t >> 2;                  // 0..63
  const int skc  = (t & 3) ^ ((t >> 3) & 3);
  const u16* Ag = A  + (size_t)(m0 + srow) * (2 * K2) + kb + skc * 8;
  const u16* Bg = Bt + (size_t)(n0 + srow) * (2 * K2) + kb + skc * 8;
  const size_t ldk = 2 * K2;

  auto STG_A = [&](int k0, int b) {
#pragma unroll
    for (int p = 0; p < 2; ++p)
      gl16(Ag + k0 + (size_t)(p * 64) * ldk, &As[b][t * 8 + p * 2048]);
  };
  auto STG_B = [&](int k0, int b) {
#pragma unroll
    for (int p = 0; p < 2; ++p)
      gl16(Bg + k0 + (size_t)(p * 64) * ldk, &Bs[b][t * 8 + p * 2048]);
  };

  f32x4 acc[4][4] = {};
  const int NT = K2 >> 5;

  STG_A(0, 0);  STG_B(0, 0);
  STG_A(32, 1); STG_B(32, 1);

  int cur = 0, nxt = 2;
  for (int kt = 0; kt < NT; ++kt) {
    if (kt + 1 < NT)
      asm volatile("s_waitcnt vmcnt(4)" ::: "memory");
    else
      asm volatile("s_waitcnt vmcnt(0)" ::: "memory");
    __builtin_amdgcn_s_barrier();
    __builtin_amdgcn_sched_barrier(0);

    const int k2 = (kt + 2) * 32;
    // phase A: B-frags + A-frags(0-1) | stage A(kt+2) | MFMA mi 0-1
    bf16x8 bfr[4], afA[2];
#pragma unroll
    for (int i = 0; i < 4; ++i)
      bfr[i] = *(const bf16x8*)((const char*)Bs[cur] +
                                ldsoff(wc * 64 + i * 16 + li, lg));
#pragma unroll
    for (int i = 0; i < 2; ++i)
      afA[i] = *(const bf16x8*)((const char*)As[cur] +
                                ldsoff(wr * 64 + i * 16 + li, lg));
    if (kt + 2 < NT) STG_A(k2, nxt);
    __builtin_amdgcn_s_setprio(1);
#pragma unroll
    for (int mi = 0; mi < 2; ++mi)
#pragma unroll
      for (int ni = 0; ni < 4; ++ni)
        acc[mi][ni] = __builtin_amdgcn_mfma_f32_16x16x32_bf16(
            afA[mi], bfr[ni], acc[mi][ni], 0, 0, 0);
    __builtin_amdgcn_s_setprio(0);

    // phase B: A-frags(2-3) | stage B(kt+2) | MFMA mi 2-3
    bf16x8 afB[2];
#pragma unroll
    for (int i = 0; i < 2; ++i)
      afB[i] = *(const bf16x8*)((const char*)As[cur] +
                                ldsoff(wr * 64 + (2 + i) * 16 + li, lg));
    if (kt + 2 < NT) STG_B(k2, nxt);
    __builtin_amdgcn_s_setprio(1);
#pragma unroll
    for (int mi = 0; mi < 2; ++mi)
#pragma unroll
      for (int ni = 0; ni < 4; ++ni)
        acc[2 + mi][ni] = __builtin_amdgcn_mfma_f32_16x16x32_bf16(
            afB[mi], bfr[ni], acc[2 + mi][ni], 0, 0, 0);
    __builtin_amdgcn_s_setprio(0);

    cur = (cur + 1 == 3) ? 0 : cur + 1;
    nxt = (nxt + 1 == 3) ? 0 : nxt + 1;
  }

  const int crow = wr * 64 + lg * 4;
  const int ccol = wc * 64 + li;
#pragma unroll
  for (int mi = 0; mi < 4; ++mi)
#pragma unroll
    for (int ni = 0; ni < 4; ++ni)
#pragma unroll
      for (int r = 0; r < 4; ++r) {
        const int gm = m0 + crow + mi * 16 + r;
        const int gn = n0 + ccol + ni * 16;
        outp[(size_t)gm * N + gn] = f2bfh(acc[mi][ni][r]);
      }
}

// FF2 reduce: out = p0 + p1 + bias + res  (4096x1024 fp32)
__global__ __launch_bounds__(256)
void ff2_reduce(const u16* __restrict__ p0, const u16* __restrict__ p1,
                const float* __restrict__ bias, const float* __restrict__ res,
                float* __restrict__ out)
{
  const unsigned stride = gridDim.x * 256;
  for (unsigned v = blockIdx.x * 256 + threadIdx.x; v < 1048576; v += stride) {
    const u16x4 a0 = *(const u16x4*)(p0 + (size_t)v * 4);
    const u16x4 a1 = *(const u16x4*)(p1 + (size_t)v * 4);
    const float4 rv = ((const float4*)res)[v];
    const int col = (v * 4) & 1023;
    float4 o;
    o.x = bf2f(a0[0]) + bf2f(a1[0]) + bias[col]     + rv.x;
    o.y = bf2f(a0[1]) + bf2f(a1[1]) + bias[col + 1] + rv.y;
    o.z = bf2f(a0[2]) + bf2f(a1[2]) + bias[col + 2] + rv.z;
    o.w = bf2f(a0[3]) + bf2f(a1[3]) + bias[col + 3] + rv.w;
    ((float4*)out)[v] = o;
  }
}

// ---------------------------------------------------------------------------
// Causal flash attention (r11, unchanged). q prescaled by 0.125*log2e.
// ---------------------------------------------------------------------------
__global__ __launch_bounds__(512, 4)
void attn_fwd(const u16* __restrict__ qb, const u16* __restrict__ kb,
              const u16* __restrict__ vtb, u16* __restrict__ ob)
{
  __shared__ u16 Ks[2][128 * 64];
  __shared__ u16 Vt[2][64 * 128];
  __shared__ u16 Ps[8][16 * 64];
  const int t = threadIdx.x, w = t >> 6, lane = t & 63;
  const int li = lane & 15, lg = lane >> 4;
  const int bh = blockIdx.y;
  const int bx = blockIdx.x;
  const int qt = (bh & 16) ? (15 - bx) : bx;
  const int q0 = qt * 128;

  const size_t qrow = (size_t)bh * 2048 + q0 + w * 16 + li;
  const bf16x8 aq0 = *(const bf16x8*)(qb + qrow * 64 + lg * 8);
  const bf16x8 aq1 = *(const bf16x8*)(qb + qrow * 64 + lg * 8 + 32);

  f32x4 o[4] = {};
  float mrun[4], lrun[4];
#pragma unroll
  for (int r = 0; r < 4; ++r) { mrun[r] = -1e30f; lrun[r] = 0.0f; }

  const u16* kbase = kb  + (size_t)bh * 2048 * 64;
  const u16* vbase = vtb + (size_t)bh * 64 * 2048;
  const int ntile = qt + 1;

  const int kchunk = (t & 7)  ^ ((t >> 3) & 7);
  const int vchunk = (t & 15) ^ ((t >> 4) & 15);
  const u16* kg = kbase + (size_t)(t >> 3) * 64 + kchunk * 8;
  const u16* vg = vbase + (size_t)(t >> 4) * 2048 + vchunk * 8;

#define STAGE(tk_, b_)                                              \
  {                                                                 \
    const int kv0s = (tk_) * 128;                                   \
    gl16(kg + (size_t)kv0s * 64,        &Ks[b_][t * 8]);            \
    gl16(kg + (size_t)(kv0s + 64) * 64, &Ks[b_][t * 8 + 4096]);     \
    gl16(vg + kv0s,                     &Vt[b_][t * 8]);            \
    gl16(vg + kv0s + (size_t)32 * 2048, &Vt[b_][t * 8 + 4096]);     \
  }

  STAGE(0, 0);
  __syncthreads();

  for (int tk = 0; tk < ntile; ++tk) {
    const int cur = tk & 1;
    const int kv0 = tk * 128;
    if (tk + 1 < ntile) STAGE(tk + 1, 1 - cur);

    f32x4 s[8];
    __builtin_amdgcn_s_setprio(1);
#pragma unroll
    for (int cf = 0; cf < 8; ++cf) {
      const int row = cf * 16 + li;
      const char* kc = (const char*)Ks[cur] + row * 128;
      const int sw = (row & 7) << 4;
      const bf16x8 bk0 = *(const bf16x8*)(kc + ((lg * 16)      ^ sw));
      const bf16x8 bk1 = *(const bf16x8*)(kc + ((lg * 16 + 64) ^ sw));
      f32x4 z = {};
      z = __builtin_amdgcn_mfma_f32_16x16x32_bf16(aq0, bk0, z, 0, 0, 0);
      z = __builtin_amdgcn_mfma_f32_16x16x32_bf16(aq1, bk1, z, 0, 0, 0);
      s[cf] = z;
    }
    __builtin_amdgcn_s_setprio(0);
    const int row0 = q0 + w * 16 + lg * 4;
    if (tk == ntile - 1) {
#pragma unroll
      for (int cf = 0; cf < 8; ++cf)
#pragma unroll
        for (int r = 0; r < 4; ++r)
          if (kv0 + cf * 16 + li > row0 + r) s[cf][r] = -1e30f;
    }

    float pmax[4];
#pragma unroll
    for (int r = 0; r < 4; ++r) {
      const float a = fmaxf(fmaxf(s[0][r], s[1][r]), fmaxf(s[2][r], s[3][r]));
      const float b = fmaxf(fmaxf(s[4][r], s[5][r]), fmaxf(s[6][r], s[7][r]));
      pmax[r] = fmaxf(a, b);
    }
    bool need = false;
#pragma unroll
    for (int r = 0; r < 4; ++r) need = need || (pmax[r] > mrun[r] + 11.5f);
    if (__any((int)need)) {
#pragma unroll
      for (int d = 1; d < 16; d <<= 1)
#pragma unroll
        for (int r = 0; r < 4; ++r)
          pmax[r] = fmaxf(pmax[r], __shfl_xor(pmax[r], d, 64));
#pragma unroll
      for (int r = 0; r < 4; ++r) {
        const float mnew = fmaxf(mrun[r], pmax[r]);
        const float scl  = AEXP2(mrun[r] - mnew);
        lrun[r] *= scl;
#pragma unroll
        for (int n = 0; n < 4; ++n) o[n][r] *= scl;
        mrun[r] = mnew;
      }
    }
#pragma unroll
    for (int cf = 0; cf < 8; ++cf)
#pragma unroll
      for (int r = 0; r < 4; ++r) {
        const float pv = AEXP2(s[cf][r] - mrun[r]);
        s[cf][r] = pv;
        lrun[r] += pv;
      }

#pragma unroll
    for (int kh = 0; kh < 2; ++kh) {
#pragma unroll
      for (int cf2 = 0; cf2 < 4; ++cf2)
#pragma unroll
        for (int r = 0; r < 4; ++r) {
          const int prow = lg * 4 + r;
          const int pcolB = (cf2 * 16 + li) * 2;
          *(u16*)((char*)Ps[w] + prow * 128 + (pcolB ^ ((prow & 7) << 4))) =
              f2bfh(s[kh * 4 + cf2][r]);
        }
      __builtin_amdgcn_s_setprio(1);
#pragma unroll
      for (int ks = 0; ks < 2; ++ks) {
        const char* pc = (const char*)Ps[w] + li * 128;
        const bf16x8 ap =
            *(const bf16x8*)(pc + ((lg * 16 + ks * 64) ^ ((li & 7) << 4)));
#pragma unroll
        for (int n = 0; n < 4; ++n) {
          const int vrow = n * 16 + li;
          const char* vc = (const char*)Vt[cur] + vrow * 256;
          const int colB = lg * 16 + ks * 64 + kh * 128;
          const bf16x8 bv =
              *(const bf16x8*)(vc + (colB ^ ((vrow & 15) << 4)));
          o[n] = __builtin_amdgcn_mfma_f32_16x16x32_bf16(ap, bv, o[n], 0, 0, 0);
        }
      }
      __builtin_amdgcn_s_setprio(0);
    }

    __syncthreads();
  }
#undef STAGE

#pragma unroll
  for (int d = 1; d < 16; d <<= 1)
#pragma unroll
    for (int r = 0; r < 4; ++r)
      lrun[r] += __shfl_xor(lrun[r], d, 64);

  float inv[4];
#pragma unroll
  for (int r = 0; r < 4; ++r) inv[r] = __builtin_amdgcn_rcpf(lrun[r]);
  const int b_ = bh >> 4, h_ = bh & 15;
#pragma unroll
  for (int n = 0; n < 4; ++n)
#pragma unroll
    for (int r = 0; r < 4; ++r) {
      const int rowg = q0 + w * 16 + lg * 4 + r;
      ob[((size_t)b_ * 2048 + rowg) * 1024 + h_ * 64 + n * 16 + li] =
          f2bfh(o[n][r] * inv[r]);
    }
}

// ---------------------------------------------------------------------------
extern "C" void kernel_launch(void* const* d_in, const int* in_sizes, int n_in,
                              void* d_out, int out_size, void* d_ws, size_t ws_size,
                              hipStream_t stream) {
  const float* x    = (const float*)d_in[0];
  const float* ln1g = (const float*)d_in[1];
  const float* ln1b = (const float*)d_in[2];
  const float* Wq   = (const float*)d_in[3];
  const float* bq   = (const float*)d_in[4];
  const float* Wk   = (const float*)d_in[5];
  const float* bk   = (const float*)d_in[6];
  const float* Wv   = (const float*)d_in[7];
  const float* bv   = (const float*)d_in[8];
  const float* Wo   = (const float*)d_in[9];
  const float* bo   = (const float*)d_in[10];
  const float* ln2g = (const float*)d_in[11];
  const float* ln2b = (const float*)d_in[12];
  const float* W1   = (const float*)d_in[13];
  const float* b1   = (const float*)d_in[14];
  const float* W2   = (const float*)d_in[15];
  const float* b2   = (const float*)d_in[16];

  char* ws = (char*)d_ws;
  const size_t MB = 1u << 20;           // total ws use: 80 MB
  u16*   hb   = (u16*)(ws + 0);         //  8 MB  LN out bf16 [4096,1024]
  u16*   Wqt  = (u16*)(ws + 8  * MB);   //  Wq^T,Wk^T,Wv^T contiguous (6 MB)
  u16*   Wkt  = (u16*)(ws + 10 * MB);
  u16*   Wvt  = (u16*)(ws + 12 * MB);
  u16*   Wot  = (u16*)(ws + 14 * MB);   //  2 MB
  u16*   W1t  = (u16*)(ws + 16 * MB);   //  8 MB  [4096][1024]
  u16*   W2t  = (u16*)(ws + 24 * MB);   //  8 MB  [1024][4096]
  u16*   qbuf = (u16*)(ws + 32 * MB);   //  8 MB  [B,H,S,DH] (prescaled)
  u16*   kbuf = (u16*)(ws + 40 * MB);   //  8 MB  [B,H,S,DH]
  u16*   aob  = (u16*)(ws + 48 * MB);   //  8 MB  attn out [B,S,D]
  u16*   vtb  = (u16*)(ws + 56 * MB);   //  8 MB  V^T [B,H,DH,S]
  float* x2   = (float*)(ws + 64 * MB); // 16 MB  fp32 residual
  u16*   h2   = hb;                     // LN2 out reuses hb
  u16*   ff1  = qbuf;                   // 32 MB spans 32..64 (all dead by FF1)
  // FF2 split-K partials (both regions dead by FF2 time):
  u16*   p0   = (u16*)(ws + 0);         //  8 MB  hb/h2 region (dead after FF1)
  u16*   p1   = (u16*)(ws + 16 * MB);   //  8 MB  W1t region   (dead after FF1)

  const dim3 blk(256);
  tconv_all<<<dim3(12288), blk, 0, stream>>>(Wq, Wk, Wv, Wo, W1, W2,
                                             Wqt, Wkt, Wvt, Wot, W1t, W2t);

  ln_fwd<<<4096, blk, 0, stream>>>(x, ln1g, ln1b, hb);

  // fused QKV: Bt = [Wq^T;Wk^T;Wv^T] rows 0..3071; V written transposed
  gemm256<EPI_QKV><<<dim3(12, 16), dim3(512), 0, stream>>>(
      hb, Wqt, bq, bk, bv, qbuf, kbuf, vtb, 3072, 1024);

  attn_fwd<<<dim3(16, 32), dim3(512), 0, stream>>>(qbuf, kbuf, vtb, aob);

  gemm_bt<EPI_RES, 64, 8><<<dim3(8, 64), blk, 0, stream>>>(
      aob, Wot, bo, x, x2, nullptr, 1024, 1024);

  ln_fwd<<<4096, blk, 0, stream>>>(x2, ln2g, ln2b, h2);

  gemm256<EPI_GELU><<<dim3(16, 16), dim3(512), 0, stream>>>(
      h2, W1t, b1, nullptr, nullptr, ff1, nullptr, nullptr, 4096, 1024);

  gemm128sk<<<dim3(512), blk, 0, stream>>>(ff1, W2t, p0, p1, 1024, 2048);
  ff2_reduce<<<dim3(2048), blk, 0, stream>>>(p0, p1, b2, x2, (float*)d_out);
}

// Round 18
// 203.076 us; speedup vs baseline: 1.0503x; 1.0503x over previous
//
#include <hip/hip_runtime.h>
#include <cstdint>
#include <cstddef>

// Transformer block, B=2 S=2048 D=1024 H=16 DH=64 DFF=4096.
// Round 18: r17 split-K reverted (pre-registered: pair >= 50us => FF2 is
// structurally saturated ~50us across 3 structures). Restore r16 (204.5us
// best) + LN1 fused into the tconv_all dispatch (data-independent halves).

#define DEV static __device__ __forceinline__

typedef unsigned short u16;
typedef __bf16 bf16x8 __attribute__((ext_vector_type(8)));
typedef u16    u16x8  __attribute__((ext_vector_type(8)));
typedef u16    u16x4  __attribute__((ext_vector_type(4)));
typedef float  f32x4  __attribute__((ext_vector_type(4)));

#define AEXP2(x) __builtin_amdgcn_exp2f(x)

DEV u16 f2bfh(float f) {             // native RNE convert (1 VALU op)
  return __builtin_bit_cast(u16, (__bf16)f);
}

// async global->LDS, 16B per lane. LDS dest must be linear in lane order.
DEV void gl16(const void* g, void* l) {
  __builtin_amdgcn_global_load_lds(
      (const __attribute__((address_space(1))) unsigned*)g,
      (__attribute__((address_space(3))) unsigned*)l, 16, 0, 0);
}

// ---------------------------------------------------------------------------
// Prep dispatch: blocks [0,12288) = all weight transposes (+fp32->bf16);
// blocks [12288,16384) = LN1 rows (independent: reads x only).
// ---------------------------------------------------------------------------
__global__ __launch_bounds__(256)
void prep_all(const float* __restrict__ w0, const float* __restrict__ w1,
              const float* __restrict__ w2, const float* __restrict__ w3,
              const float* __restrict__ W1, const float* __restrict__ W2,
              u16* __restrict__ q0, u16* __restrict__ q1,
              u16* __restrict__ q2, u16* __restrict__ q3,
              u16* __restrict__ W1t, u16* __restrict__ W2t,
              const float* __restrict__ x, const float* __restrict__ g,
              const float* __restrict__ b, u16* __restrict__ hb)
{
  __shared__ float tile[32][33];
  __shared__ float sh[8];
  const int bid = blockIdx.x;
  if (bid >= 12288) {
    // ---- LN1 row ----
    const int row = bid - 12288, t = threadIdx.x;
    const float4 v = ((const float4*)(x + (size_t)row * 1024))[t];
    float s1 = v.x + v.y + v.z + v.w;
    float s2 = v.x*v.x + v.y*v.y + v.z*v.z + v.w*v.w;
#pragma unroll
    for (int d = 1; d < 64; d <<= 1) {
      s1 += __shfl_xor(s1, d, 64);
      s2 += __shfl_xor(s2, d, 64);
    }
    const int w = t >> 6;
    if ((t & 63) == 0) { sh[w] = s1; sh[w + 4] = s2; }
    __syncthreads();
    s1 = sh[0] + sh[1] + sh[2] + sh[3];
    s2 = sh[4] + sh[5] + sh[6] + sh[7];
    const float mu  = s1 * (1.0f / 1024.0f);
    const float var = s2 * (1.0f / 1024.0f) - mu * mu;
    const float rs  = rsqrtf(var + 1e-5f);
    const float4 gv = ((const float4*)g)[t];
    const float4 bv = ((const float4*)b)[t];
    u16x4 o;
    o[0] = f2bfh((v.x - mu) * rs * gv.x + bv.x);
    o[1] = f2bfh((v.y - mu) * rs * gv.y + bv.y);
    o[2] = f2bfh((v.z - mu) * rs * gv.z + bv.z);
    o[3] = f2bfh((v.w - mu) * rs * gv.w + bv.w);
    *(u16x4*)(hb + (size_t)row * 1024 + t * 4) = o;
    return;
  }
  // ---- weight transpose tile ----
  const float* in; u16* out; int R, C, r0, c0;
  if (bid < 4096) {
    const int z = bid >> 10, l = bid & 1023;
    in = z == 0 ? w0 : z == 1 ? w1 : z == 2 ? w2 : w3;
    out = z == 0 ? q0 : z == 1 ? q1 : z == 2 ? q2 : q3;
    R = 1024; C = 1024; r0 = (l >> 5) * 32; c0 = (l & 31) * 32;
  } else if (bid < 8192) {
    const int l = bid - 4096;
    in = W1; out = W1t; R = 1024; C = 4096;
    r0 = (l >> 7) * 32; c0 = (l & 127) * 32;
  } else {
    const int l = bid - 8192;
    in = W2; out = W2t; R = 4096; C = 1024;
    r0 = (l >> 5) * 32; c0 = (l & 31) * 32;
  }
  const int tx = threadIdx.x & 31, ty = threadIdx.x >> 5;   // 32 x 8
#pragma unroll
  for (int i = 0; i < 4; ++i)
    tile[ty + 8*i][tx] = in[(size_t)(r0 + ty + 8*i) * C + c0 + tx];
  __syncthreads();
#pragma unroll
  for (int i = 0; i < 4; ++i)
    out[(size_t)(c0 + ty + 8*i) * R + r0 + tx] = f2bfh(tile[tx][ty + 8*i]);
}

// ---------------------------------------------------------------------------
// LayerNorm over D=1024, one block (256 threads) per row, out bf16
// ---------------------------------------------------------------------------
__global__ __launch_bounds__(256)
void ln_fwd(const float* __restrict__ x, const float* __restrict__ g,
            const float* __restrict__ b, u16* __restrict__ out)
{
  const int row = blockIdx.x, t = threadIdx.x;
  const float4 v = ((const float4*)(x + (size_t)row * 1024))[t];
  float s1 = v.x + v.y + v.z + v.w;
  float s2 = v.x*v.x + v.y*v.y + v.z*v.z + v.w*v.w;
#pragma unroll
  for (int d = 1; d < 64; d <<= 1) {
    s1 += __shfl_xor(s1, d, 64);
    s2 += __shfl_xor(s2, d, 64);
  }
  __shared__ float sh[8];
  const int w = t >> 6;
  if ((t & 63) == 0) { sh[w] = s1; sh[w + 4] = s2; }
  __syncthreads();
  s1 = sh[0] + sh[1] + sh[2] + sh[3];
  s2 = sh[4] + sh[5] + sh[6] + sh[7];
  const float mu  = s1 * (1.0f / 1024.0f);
  const float var = s2 * (1.0f / 1024.0f) - mu * mu;
  const float rs  = rsqrtf(var + 1e-5f);
  const float4 gv = ((const float4*)g)[t];
  const float4 bv = ((const float4*)b)[t];
  u16x4 o;
  o[0] = f2bfh((v.x - mu) * rs * gv.x + bv.x);
  o[1] = f2bfh((v.y - mu) * rs * gv.y + bv.y);
  o[2] = f2bfh((v.z - mu) * rs * gv.z + bv.z);
  o[3] = f2bfh((v.w - mu) * rs * gv.w + bv.w);
  *(u16x4*)(out + (size_t)row * 1024 + t * 4) = o;
}

#define EPI_QKV  0
#define EPI_RES  1
#define EPI_GELU 2

#define QSCALE 0.180421f   // 0.125 * log2(e): softmax runs in exp2 domain

// paired-row LDS layout helper (32-col tiles):
// byte(R,kc) = (R>>1)*128 + (R&1)*64 + ((kc ^ ((R>>1)&3))<<4)
DEV int ldsoff(int R, int kc) {
  return (R >> 1) * 128 + (R & 1) * 64 + ((kc ^ ((R >> 1) & 3)) << 4);
}

// ---------------------------------------------------------------------------
// 256x256 GEMM (QKV/FF1), 8 waves (2Mx4N, 128x64/wave), BK=32, 3-buffer
// depth-2 phase-interleaved pipeline, counted vmcnt(4), paired-row LDS.
// ---------------------------------------------------------------------------
template<int EPI>
__global__ __launch_bounds__(512, 2)
void gemm256(const u16* __restrict__ A, const u16* __restrict__ Bt,
             const float* __restrict__ b0, const float* __restrict__ b1,
             const float* __restrict__ b2,
             u16* __restrict__ o0, u16* __restrict__ o1, u16* __restrict__ o2,
             int N, int K)
{
  __shared__ u16 As[3][8192];   // 16KB each: 256 rows x 32 cols, paired-row
  __shared__ u16 Bs[3][8192];
  const int t = threadIdx.x, lane = t & 63, w = t >> 6;
  const int wr = w >> 2, wc = w & 3;
  const int d = blockIdx.x + gridDim.x * blockIdx.y;
  const int rr = d >> 3;
  const int m0 = ((d & 7) * 2 + (rr & 1)) * 256;
  const int n0 = (rr >> 1) * 256;
  const int li = lane & 15, lg = lane >> 4;

  const int srow = t >> 2;                       // 0..127
  const int skc  = (t & 3) ^ ((t >> 3) & 3);
  const u16* Ag = A  + (size_t)(m0 + srow) * K + skc * 8;
  const u16* Bg = Bt + (size_t)(n0 + srow) * K + skc * 8;

  auto STG_A = [&](int k0, int b) {
#pragma unroll
    for (int p = 0; p < 2; ++p)
      gl16(Ag + k0 + (size_t)(p * 128) * K, &As[b][t * 8 + p * 4096]);
  };
  auto STG_B = [&](int k0, int b) {
#pragma unroll
    for (int p = 0; p < 2; ++p)
      gl16(Bg + k0 + (size_t)(p * 128) * K, &Bs[b][t * 8 + p * 4096]);
  };

  f32x4 acc[8][4] = {};
  const int NT = K >> 5;

  STG_A(0, 0);  STG_B(0, 0);
  STG_A(32, 1); STG_B(32, 1);

  int cur = 0, nxt = 2;
  for (int kt = 0; kt < NT; ++kt) {
    if (kt + 1 < NT)
      asm volatile("s_waitcnt vmcnt(4)" ::: "memory");
    else
      asm volatile("s_waitcnt vmcnt(0)" ::: "memory");
    __builtin_amdgcn_s_barrier();
    __builtin_amdgcn_sched_barrier(0);

    const int k2 = (kt + 2) * 32;
    bf16x8 bfr[4], afA[4];
#pragma unroll
    for (int i = 0; i < 4; ++i)
      bfr[i] = *(const bf16x8*)((const char*)Bs[cur] +
                                ldsoff(wc * 64 + i * 16 + li, lg));
#pragma unroll
    for (int i = 0; i < 4; ++i)
      afA[i] = *(const bf16x8*)((const char*)As[cur] +
                                ldsoff(wr * 128 + i * 16 + li, lg));
    if (kt + 2 < NT) STG_A(k2, nxt);
    __builtin_amdgcn_s_setprio(1);
#pragma unroll
    for (int mi = 0; mi < 4; ++mi)
#pragma unroll
      for (int ni = 0; ni < 4; ++ni)
        acc[mi][ni] = __builtin_amdgcn_mfma_f32_16x16x32_bf16(
            afA[mi], bfr[ni], acc[mi][ni], 0, 0, 0);
    __builtin_amdgcn_s_setprio(0);

    bf16x8 afB[4];
#pragma unroll
    for (int i = 0; i < 4; ++i)
      afB[i] = *(const bf16x8*)((const char*)As[cur] +
                                ldsoff(wr * 128 + (4 + i) * 16 + li, lg));
    if (kt + 2 < NT) STG_B(k2, nxt);
    __builtin_amdgcn_s_setprio(1);
#pragma unroll
    for (int mi = 0; mi < 4; ++mi)
#pragma unroll
      for (int ni = 0; ni < 4; ++ni)
        acc[4 + mi][ni] = __builtin_amdgcn_mfma_f32_16x16x32_bf16(
            afB[mi], bfr[ni], acc[4 + mi][ni], 0, 0, 0);
    __builtin_amdgcn_s_setprio(0);

    cur = (cur + 1 == 3) ? 0 : cur + 1;
    nxt = (nxt + 1 == 3) ? 0 : nxt + 1;
  }

  const int crow = wr * 128 + lg * 4;
  const int ccol = wc * 64 + li;

  if (EPI == EPI_QKV) {
    const int which = n0 >> 10;                     // 0=q 1=k 2=v (uniform)
    const float* bias = which == 0 ? b0 : which == 1 ? b1 : b2;
    const int nn0 = n0 & 1023;
    if (which == 2) {
      // V: write transposed [BH][64][2048]; r -> consecutive s => u16x4 store
#pragma unroll
      for (int mi = 0; mi < 8; ++mi)
#pragma unroll
        for (int ni = 0; ni < 4; ++ni) {
          const int gm0 = m0 + crow + mi * 16;
          const int b_ = gm0 >> 11, s_ = gm0 & 2047;
          const int gc = nn0 + ccol + ni * 16;
          const int h_ = gc >> 6, d_ = gc & 63;
          u16x4 pk;
#pragma unroll
          for (int r = 0; r < 4; ++r) pk[r] = f2bfh(acc[mi][ni][r] + bias[gc]);
          *(u16x4*)(o2 + ((size_t)(b_ * 16 + h_) * 64 + d_) * 2048 + s_) = pk;
        }
    } else {
      u16* outp = which == 0 ? o0 : o1;
      const float sc = which == 0 ? QSCALE : 1.0f;
#pragma unroll
      for (int mi = 0; mi < 8; ++mi)
#pragma unroll
        for (int ni = 0; ni < 4; ++ni)
#pragma unroll
          for (int r = 0; r < 4; ++r) {
            const int gm = m0 + crow + mi * 16 + r;
            const int gc = nn0 + ccol + ni * 16;
            const float v = (acc[mi][ni][r] + bias[gc]) * sc;
            const int b_ = gm >> 11, s_ = gm & 2047;
            const int h_ = gc >> 6,  d_ = gc & 63;
            outp[((size_t)(b_ * 16 + h_) * 2048 + s_) * 64 + d_] = f2bfh(v);
          }
    }
  } else {
#pragma unroll
    for (int mi = 0; mi < 8; ++mi)
#pragma unroll
      for (int ni = 0; ni < 4; ++ni)
#pragma unroll
        for (int r = 0; r < 4; ++r) {
          const int gm = m0 + crow + mi * 16 + r;
          const int gn = n0 + ccol + ni * 16;
          const float v = acc[mi][ni][r] + b0[gn];
          const float y = 0.7978845608f * (v + 0.044715f * v * v * v);
          const float e = AEXP2(fminf(y * 2.8853900818f, 80.0f));
          const float gl = v * e * __builtin_amdgcn_rcpf(e + 1.0f);
          o0[(size_t)gm * N + gn] = f2bfh(gl);
        }
  }
}

// ---------------------------------------------------------------------------
// Skinny GEMM (Wo/FF2): BM=64 x 128, 4 waves, BK=64, 3-buffer depth-2
// pipeline with counted vmcnt(6). XCD swizzle CM=8 (XCD owns m-chunk).
// out fp32 = acc + bias + res.
// ---------------------------------------------------------------------------
template<int EPI, int BM, int CM>
__global__ __launch_bounds__(256)
void gemm_bt(const u16* __restrict__ A, const u16* __restrict__ Bt,
             const float* __restrict__ b0, const float* __restrict__ res,
             float* __restrict__ outf, u16* __restrict__ o0,
             int N, int K)
{
  constexpr int MI = BM / 32;
  constexpr int RA = BM / 32;
  static_assert(BM == 64, "vmcnt(6) assumes 6 loads/step");
  __shared__ u16 As[3][BM * 64];
  __shared__ u16 Bs[3][128 * 64];
  const int t = threadIdx.x, lane = t & 63, w = t >> 6;
  const int wr = w >> 1, wc = w & 1;
  const int d = blockIdx.x + gridDim.x * blockIdx.y;
  const int rr = d >> 3;
  const int m0 = ((d & 7) * CM + rr % CM) * BM;
  const int n0 = (rr / CM) * 128;
  const int li = lane & 15, lg = lane >> 4;

  const int srow = t >> 3;
  const int schunk = (t & 7) ^ (srow & 7);
  const u16* Ag = A  + (size_t)(m0 + srow) * K + schunk * 8;
  const u16* Bg = Bt + (size_t)(n0 + srow) * K + schunk * 8;

  auto STG = [&](int k0, int b) {
#pragma unroll
    for (int p = 0; p < RA; ++p)
      gl16(Ag + k0 + (size_t)(p * 32) * K, &As[b][t * 8 + p * 2048]);
#pragma unroll
    for (int p = 0; p < 4; ++p)
      gl16(Bg + k0 + (size_t)(p * 32) * K, &Bs[b][t * 8 + p * 2048]);
  };

  f32x4 acc[MI][4] = {};
  const int swz = (li & 7) << 4;

  auto COMPUTE = [&](int cur) {
#pragma unroll
    for (int ks = 0; ks < 2; ++ks) {
      bf16x8 af[MI], bfr[4];
#pragma unroll
      for (int i = 0; i < MI; ++i) {
        const int Ra = wr * (MI * 16) + i * 16 + li;
        af[i] = *(const bf16x8*)((const char*)As[cur] + Ra * 128 +
                                 ((ks * 64 + lg * 16) ^ swz));
      }
#pragma unroll
      for (int i = 0; i < 4; ++i) {
        const int Rb = wc * 64 + i * 16 + li;
        bfr[i] = *(const bf16x8*)((const char*)Bs[cur] + Rb * 128 +
                                  ((ks * 64 + lg * 16) ^ swz));
      }
#pragma unroll
      for (int mi = 0; mi < MI; ++mi)
#pragma unroll
        for (int ni = 0; ni < 4; ++ni)
          acc[mi][ni] = __builtin_amdgcn_mfma_f32_16x16x32_bf16(
              af[mi], bfr[ni], acc[mi][ni], 0, 0, 0);
    }
  };

  STG(0, 0);
  if (64 < K) STG(64, 1);
  int cur = 0;
  for (int k0 = 0; k0 < K; k0 += 64) {
    if (k0 + 64 < K)
      asm volatile("s_waitcnt vmcnt(6)" ::: "memory");
    else
      asm volatile("s_waitcnt vmcnt(0)" ::: "memory");
    __builtin_amdgcn_s_barrier();
    __builtin_amdgcn_sched_barrier(0);
    COMPUTE(cur);
    if (k0 + 128 < K) {
      int nxt = cur + 2; if (nxt >= 3) nxt -= 3;
      STG(k0 + 128, nxt);
    }
    cur = (cur + 1 == 3) ? 0 : cur + 1;
  }

  const int crow = wr * (MI * 16) + lg * 4;
  const int ccol = wc * 64 + li;
#pragma unroll
  for (int mi = 0; mi < MI; ++mi)
#pragma unroll
    for (int ni = 0; ni < 4; ++ni)
#pragma unroll
      for (int r = 0; r < 4; ++r) {
        const int gm = m0 + crow + mi * 16 + r;
        const int gn = n0 + ccol + ni * 16;
        const float v = acc[mi][ni][r] + b0[gn];
        const size_t o = (size_t)gm * N + gn;
        outf[o] = v + res[o];
      }
}

// ---------------------------------------------------------------------------
// Causal flash attention (r11, unchanged). q prescaled by 0.125*log2e.
// ---------------------------------------------------------------------------
__global__ __launch_bounds__(512, 4)
void attn_fwd(const u16* __restrict__ qb, const u16* __restrict__ kb,
              const u16* __restrict__ vtb, u16* __restrict__ ob)
{
  __shared__ u16 Ks[2][128 * 64];
  __shared__ u16 Vt[2][64 * 128];
  __shared__ u16 Ps[8][16 * 64];
  const int t = threadIdx.x, w = t >> 6, lane = t & 63;
  const int li = lane & 15, lg = lane >> 4;
  const int bh = blockIdx.y;
  const int bx = blockIdx.x;
  const int qt = (bh & 16) ? (15 - bx) : bx;
  const int q0 = qt * 128;

  const size_t qrow = (size_t)bh * 2048 + q0 + w * 16 + li;
  const bf16x8 aq0 = *(const bf16x8*)(qb + qrow * 64 + lg * 8);
  const bf16x8 aq1 = *(const bf16x8*)(qb + qrow * 64 + lg * 8 + 32);

  f32x4 o[4] = {};
  float mrun[4], lrun[4];
#pragma unroll
  for (int r = 0; r < 4; ++r) { mrun[r] = -1e30f; lrun[r] = 0.0f; }

  const u16* kbase = kb  + (size_t)bh * 2048 * 64;
  const u16* vbase = vtb + (size_t)bh * 64 * 2048;
  const int ntile = qt + 1;

  const int kchunk = (t & 7)  ^ ((t >> 3) & 7);
  const int vchunk = (t & 15) ^ ((t >> 4) & 15);
  const u16* kg = kbase + (size_t)(t >> 3) * 64 + kchunk * 8;
  const u16* vg = vbase + (size_t)(t >> 4) * 2048 + vchunk * 8;

#define STAGE(tk_, b_)                                              \
  {                                                                 \
    const int kv0s = (tk_) * 128;                                   \
    gl16(kg + (size_t)kv0s * 64,        &Ks[b_][t * 8]);            \
    gl16(kg + (size_t)(kv0s + 64) * 64, &Ks[b_][t * 8 + 4096]);     \
    gl16(vg + kv0s,                     &Vt[b_][t * 8]);            \
    gl16(vg + kv0s + (size_t)32 * 2048, &Vt[b_][t * 8 + 4096]);     \
  }

  STAGE(0, 0);
  __syncthreads();

  for (int tk = 0; tk < ntile; ++tk) {
    const int cur = tk & 1;
    const int kv0 = tk * 128;
    if (tk + 1 < ntile) STAGE(tk + 1, 1 - cur);

    f32x4 s[8];
    __builtin_amdgcn_s_setprio(1);
#pragma unroll
    for (int cf = 0; cf < 8; ++cf) {
      const int row = cf * 16 + li;
      const char* kc = (const char*)Ks[cur] + row * 128;
      const int sw = (row & 7) << 4;
      const bf16x8 bk0 = *(const bf16x8*)(kc + ((lg * 16)      ^ sw));
      const bf16x8 bk1 = *(const bf16x8*)(kc + ((lg * 16 + 64) ^ sw));
      f32x4 z = {};
      z = __builtin_amdgcn_mfma_f32_16x16x32_bf16(aq0, bk0, z, 0, 0, 0);
      z = __builtin_amdgcn_mfma_f32_16x16x32_bf16(aq1, bk1, z, 0, 0, 0);
      s[cf] = z;
    }
    __builtin_amdgcn_s_setprio(0);
    const int row0 = q0 + w * 16 + lg * 4;
    if (tk == ntile - 1) {
#pragma unroll
      for (int cf = 0; cf < 8; ++cf)
#pragma unroll
        for (int r = 0; r < 4; ++r)
          if (kv0 + cf * 16 + li > row0 + r) s[cf][r] = -1e30f;
    }

    float pmax[4];
#pragma unroll
    for (int r = 0; r < 4; ++r) {
      const float a = fmaxf(fmaxf(s[0][r], s[1][r]), fmaxf(s[2][r], s[3][r]));
      const float b = fmaxf(fmaxf(s[4][r], s[5][r]), fmaxf(s[6][r], s[7][r]));
      pmax[r] = fmaxf(a, b);
    }
    bool need = false;
#pragma unroll
    for (int r = 0; r < 4; ++r) need = need || (pmax[r] > mrun[r] + 11.5f);
    if (__any((int)need)) {
#pragma unroll
      for (int d = 1; d < 16; d <<= 1)
#pragma unroll
        for (int r = 0; r < 4; ++r)
          pmax[r] = fmaxf(pmax[r], __shfl_xor(pmax[r], d, 64));
#pragma unroll
      for (int r = 0; r < 4; ++r) {
        const float mnew = fmaxf(mrun[r], pmax[r]);
        const float scl  = AEXP2(mrun[r] - mnew);
        lrun[r] *= scl;
#pragma unroll
        for (int n = 0; n < 4; ++n) o[n][r] *= scl;
        mrun[r] = mnew;
      }
    }
#pragma unroll
    for (int cf = 0; cf < 8; ++cf)
#pragma unroll
      for (int r = 0; r < 4; ++r) {
        const float pv = AEXP2(s[cf][r] - mrun[r]);
        s[cf][r] = pv;
        lrun[r] += pv;
      }

#pragma unroll
    for (int kh = 0; kh < 2; ++kh) {
#pragma unroll
      for (int cf2 = 0; cf2 < 4; ++cf2)
#pragma unroll
        for (int r = 0; r < 4; ++r) {
          const int prow = lg * 4 + r;
          const int pcolB = (cf2 * 16 + li) * 2;
          *(u16*)((char*)Ps[w] + prow * 128 + (pcolB ^ ((prow & 7) << 4))) =
              f2bfh(s[kh * 4 + cf2][r]);
        }
      __builtin_amdgcn_s_setprio(1);
#pragma unroll
      for (int ks = 0; ks < 2; ++ks) {
        const char* pc = (const char*)Ps[w] + li * 128;
        const bf16x8 ap =
            *(const bf16x8*)(pc + ((lg * 16 + ks * 64) ^ ((li & 7) << 4)));
#pragma unroll
        for (int n = 0; n < 4; ++n) {
          const int vrow = n * 16 + li;
          const char* vc = (const char*)Vt[cur] + vrow * 256;
          const int colB = lg * 16 + ks * 64 + kh * 128;
          const bf16x8 bv =
              *(const bf16x8*)(vc + (colB ^ ((vrow & 15) << 4)));
          o[n] = __builtin_amdgcn_mfma_f32_16x16x32_bf16(ap, bv, o[n], 0, 0, 0);
        }
      }
      __builtin_amdgcn_s_setprio(0);
    }

    __syncthreads();
  }
#undef STAGE

#pragma unroll
  for (int d = 1; d < 16; d <<= 1)
#pragma unroll
    for (int r = 0; r < 4; ++r)
      lrun[r] += __shfl_xor(lrun[r], d, 64);

  float inv[4];
#pragma unroll
  for (int r = 0; r < 4; ++r) inv[r] = __builtin_amdgcn_rcpf(lrun[r]);
  const int b_ = bh >> 4, h_ = bh & 15;
#pragma unroll
  for (int n = 0; n < 4; ++n)
#pragma unroll
    for (int r = 0; r < 4; ++r) {
      const int rowg = q0 + w * 16 + lg * 4 + r;
      ob[((size_t)b_ * 2048 + rowg) * 1024 + h_ * 64 + n * 16 + li] =
          f2bfh(o[n][r] * inv[r]);
    }
}

// ---------------------------------------------------------------------------
extern "C" void kernel_launch(void* const* d_in, const int* in_sizes, int n_in,
                              void* d_out, int out_size, void* d_ws, size_t ws_size,
                              hipStream_t stream) {
  const float* x    = (const float*)d_in[0];
  const float* ln1g = (const float*)d_in[1];
  const float* ln1b = (const float*)d_in[2];
  const float* Wq   = (const float*)d_in[3];
  const float* bq   = (const float*)d_in[4];
  const float* Wk   = (const float*)d_in[5];
  const float* bk   = (const float*)d_in[6];
  const float* Wv   = (const float*)d_in[7];
  const float* bv   = (const float*)d_in[8];
  const float* Wo   = (const float*)d_in[9];
  const float* bo   = (const float*)d_in[10];
  const float* ln2g = (const float*)d_in[11];
  const float* ln2b = (const float*)d_in[12];
  const float* W1   = (const float*)d_in[13];
  const float* b1   = (const float*)d_in[14];
  const float* W2   = (const float*)d_in[15];
  const float* b2   = (const float*)d_in[16];

  char* ws = (char*)d_ws;
  const size_t MB = 1u << 20;           // total ws use: 80 MB
  u16*   hb   = (u16*)(ws + 0);         //  8 MB  LN out bf16 [4096,1024]
  u16*   Wqt  = (u16*)(ws + 8  * MB);   //  Wq^T,Wk^T,Wv^T contiguous (6 MB)
  u16*   Wkt  = (u16*)(ws + 10 * MB);
  u16*   Wvt  = (u16*)(ws + 12 * MB);
  u16*   Wot  = (u16*)(ws + 14 * MB);   //  2 MB
  u16*   W1t  = (u16*)(ws + 16 * MB);   //  8 MB  [4096][1024]
  u16*   W2t  = (u16*)(ws + 24 * MB);   //  8 MB  [1024][4096]
  u16*   qbuf = (u16*)(ws + 32 * MB);   //  8 MB  [B,H,S,DH] (prescaled)
  u16*   kbuf = (u16*)(ws + 40 * MB);   //  8 MB  [B,H,S,DH]
  u16*   aob  = (u16*)(ws + 48 * MB);   //  8 MB  attn out [B,S,D]
  u16*   vtb  = (u16*)(ws + 56 * MB);   //  8 MB  V^T [B,H,DH,S]
  float* x2   = (float*)(ws + 64 * MB); // 16 MB  fp32 residual
  u16*   h2   = hb;                     // LN2 out reuses hb
  u16*   ff1  = qbuf;                   // 32 MB spans 32..64 (all dead by FF1)

  const dim3 blk(256);
  // transposes + LN1 in one dispatch (independent halves)
  prep_all<<<dim3(16384), blk, 0, stream>>>(Wq, Wk, Wv, Wo, W1, W2,
                                            Wqt, Wkt, Wvt, Wot, W1t, W2t,
                                            x, ln1g, ln1b, hb);

  // fused QKV: Bt = [Wq^T;Wk^T;Wv^T] rows 0..3071; V written transposed
  gemm256<EPI_QKV><<<dim3(12, 16), dim3(512), 0, stream>>>(
      hb, Wqt, bq, bk, bv, qbuf, kbuf, vtb, 3072, 1024);

  attn_fwd<<<dim3(16, 32), dim3(512), 0, stream>>>(qbuf, kbuf, vtb, aob);

  gemm_bt<EPI_RES, 64, 8><<<dim3(8, 64), blk, 0, stream>>>(
      aob, Wot, bo, x, x2, nullptr, 1024, 1024);

  ln_fwd<<<4096, blk, 0, stream>>>(x2, ln2g, ln2b, h2);

  gemm256<EPI_GELU><<<dim3(16, 16), dim3(512), 0, stream>>>(
      h2, W1t, b1, nullptr, nullptr, ff1, nullptr, nullptr, 4096, 1024);

  gemm_bt<EPI_RES, 64, 8><<<dim3(8, 64), blk, 0, stream>>>(
      ff1, W2t, b2, x2, (float*)d_out, nullptr, 1024, 4096);
}

// Round 19
// 202.341 us; speedup vs baseline: 1.0542x; 1.0036x over previous
//
#include <hip/hip_runtime.h>
#include <cstdint>
#include <cstddef>

// Transformer block, B=2 S=2048 D=1024 H=16 DH=64 DFF=4096.
// Round 19 (lock-in): r18 verbatim — session best 203.1us (2.45x over r1).
// prep_all (transposes + LN1 fused) -> gemm256 QKV (phase-interleaved,
// counted vmcnt(4), paired-row LDS) -> attn (dbuf, bh&16 balance, exp2
// softmax, per-lane defer-max) -> gemm_bt Wo (3-buf depth-2 vmcnt(6)) ->
// LN2 -> gemm256 FF1 (+GELU) -> gemm_bt FF2. FF2/attn declared saturated
// per r13-r17 structural probes.

#define DEV static __device__ __forceinline__

typedef unsigned short u16;
typedef __bf16 bf16x8 __attribute__((ext_vector_type(8)));
typedef u16    u16x8  __attribute__((ext_vector_type(8)));
typedef u16    u16x4  __attribute__((ext_vector_type(4)));
typedef float  f32x4  __attribute__((ext_vector_type(4)));

#define AEXP2(x) __builtin_amdgcn_exp2f(x)

DEV u16 f2bfh(float f) {             // native RNE convert (1 VALU op)
  return __builtin_bit_cast(u16, (__bf16)f);
}

// async global->LDS, 16B per lane. LDS dest must be linear in lane order.
DEV void gl16(const void* g, void* l) {
  __builtin_amdgcn_global_load_lds(
      (const __attribute__((address_space(1))) unsigned*)g,
      (__attribute__((address_space(3))) unsigned*)l, 16, 0, 0);
}

// ---------------------------------------------------------------------------
// Prep dispatch: blocks [0,12288) = all weight transposes (+fp32->bf16);
// blocks [12288,16384) = LN1 rows (independent: reads x only).
// ---------------------------------------------------------------------------
__global__ __launch_bounds__(256)
void prep_all(const float* __restrict__ w0, const float* __restrict__ w1,
              const float* __restrict__ w2, const float* __restrict__ w3,
              const float* __restrict__ W1, const float* __restrict__ W2,
              u16* __restrict__ q0, u16* __restrict__ q1,
              u16* __restrict__ q2, u16* __restrict__ q3,
              u16* __restrict__ W1t, u16* __restrict__ W2t,
              const float* __restrict__ x, const float* __restrict__ g,
              const float* __restrict__ b, u16* __restrict__ hb)
{
  __shared__ float tile[32][33];
  __shared__ float sh[8];
  const int bid = blockIdx.x;
  if (bid >= 12288) {
    // ---- LN1 row ----
    const int row = bid - 12288, t = threadIdx.x;
    const float4 v = ((const float4*)(x + (size_t)row * 1024))[t];
    float s1 = v.x + v.y + v.z + v.w;
    float s2 = v.x*v.x + v.y*v.y + v.z*v.z + v.w*v.w;
#pragma unroll
    for (int d = 1; d < 64; d <<= 1) {
      s1 += __shfl_xor(s1, d, 64);
      s2 += __shfl_xor(s2, d, 64);
    }
    const int w = t >> 6;
    if ((t & 63) == 0) { sh[w] = s1; sh[w + 4] = s2; }
    __syncthreads();
    s1 = sh[0] + sh[1] + sh[2] + sh[3];
    s2 = sh[4] + sh[5] + sh[6] + sh[7];
    const float mu  = s1 * (1.0f / 1024.0f);
    const float var = s2 * (1.0f / 1024.0f) - mu * mu;
    const float rs  = rsqrtf(var + 1e-5f);
    const float4 gv = ((const float4*)g)[t];
    const float4 bv = ((const float4*)b)[t];
    u16x4 o;
    o[0] = f2bfh((v.x - mu) * rs * gv.x + bv.x);
    o[1] = f2bfh((v.y - mu) * rs * gv.y + bv.y);
    o[2] = f2bfh((v.z - mu) * rs * gv.z + bv.z);
    o[3] = f2bfh((v.w - mu) * rs * gv.w + bv.w);
    *(u16x4*)(hb + (size_t)row * 1024 + t * 4) = o;
    return;
  }
  // ---- weight transpose tile ----
  const float* in; u16* out; int R, C, r0, c0;
  if (bid < 4096) {
    const int z = bid >> 10, l = bid & 1023;
    in = z == 0 ? w0 : z == 1 ? w1 : z == 2 ? w2 : w3;
    out = z == 0 ? q0 : z == 1 ? q1 : z == 2 ? q2 : q3;
    R = 1024; C = 1024; r0 = (l >> 5) * 32; c0 = (l & 31) * 32;
  } else if (bid < 8192) {
    const int l = bid - 4096;
    in = W1; out = W1t; R = 1024; C = 4096;
    r0 = (l >> 7) * 32; c0 = (l & 127) * 32;
  } else {
    const int l = bid - 8192;
    in = W2; out = W2t; R = 4096; C = 1024;
    r0 = (l >> 5) * 32; c0 = (l & 31) * 32;
  }
  const int tx = threadIdx.x & 31, ty = threadIdx.x >> 5;   // 32 x 8
#pragma unroll
  for (int i = 0; i < 4; ++i)
    tile[ty + 8*i][tx] = in[(size_t)(r0 + ty + 8*i) * C + c0 + tx];
  __syncthreads();
#pragma unroll
  for (int i = 0; i < 4; ++i)
    out[(size_t)(c0 + ty + 8*i) * R + r0 + tx] = f2bfh(tile[tx][ty + 8*i]);
}

// ---------------------------------------------------------------------------
// LayerNorm over D=1024, one block (256 threads) per row, out bf16
// ---------------------------------------------------------------------------
__global__ __launch_bounds__(256)
void ln_fwd(const float* __restrict__ x, const float* __restrict__ g,
            const float* __restrict__ b, u16* __restrict__ out)
{
  const int row = blockIdx.x, t = threadIdx.x;
  const float4 v = ((const float4*)(x + (size_t)row * 1024))[t];
  float s1 = v.x + v.y + v.z + v.w;
  float s2 = v.x*v.x + v.y*v.y + v.z*v.z + v.w*v.w;
#pragma unroll
  for (int d = 1; d < 64; d <<= 1) {
    s1 += __shfl_xor(s1, d, 64);
    s2 += __shfl_xor(s2, d, 64);
  }
  __shared__ float sh[8];
  const int w = t >> 6;
  if ((t & 63) == 0) { sh[w] = s1; sh[w + 4] = s2; }
  __syncthreads();
  s1 = sh[0] + sh[1] + sh[2] + sh[3];
  s2 = sh[4] + sh[5] + sh[6] + sh[7];
  const float mu  = s1 * (1.0f / 1024.0f);
  const float var = s2 * (1.0f / 1024.0f) - mu * mu;
  const float rs  = rsqrtf(var + 1e-5f);
  const float4 gv = ((const float4*)g)[t];
  const float4 bv = ((const float4*)b)[t];
  u16x4 o;
  o[0] = f2bfh((v.x - mu) * rs * gv.x + bv.x);
  o[1] = f2bfh((v.y - mu) * rs * gv.y + bv.y);
  o[2] = f2bfh((v.z - mu) * rs * gv.z + bv.z);
  o[3] = f2bfh((v.w - mu) * rs * gv.w + bv.w);
  *(u16x4*)(out + (size_t)row * 1024 + t * 4) = o;
}

#define EPI_QKV  0
#define EPI_RES  1
#define EPI_GELU 2

#define QSCALE 0.180421f   // 0.125 * log2(e): softmax runs in exp2 domain

// paired-row LDS layout helper (32-col tiles):
// byte(R,kc) = (R>>1)*128 + (R&1)*64 + ((kc ^ ((R>>1)&3))<<4)
DEV int ldsoff(int R, int kc) {
  return (R >> 1) * 128 + (R & 1) * 64 + ((kc ^ ((R >> 1) & 3)) << 4);
}

// ---------------------------------------------------------------------------
// 256x256 GEMM (QKV/FF1), 8 waves (2Mx4N, 128x64/wave), BK=32, 3-buffer
// depth-2 phase-interleaved pipeline, counted vmcnt(4), paired-row LDS.
// ---------------------------------------------------------------------------
template<int EPI>
__global__ __launch_bounds__(512, 2)
void gemm256(const u16* __restrict__ A, const u16* __restrict__ Bt,
             const float* __restrict__ b0, const float* __restrict__ b1,
             const float* __restrict__ b2,
             u16* __restrict__ o0, u16* __restrict__ o1, u16* __restrict__ o2,
             int N, int K)
{
  __shared__ u16 As[3][8192];   // 16KB each: 256 rows x 32 cols, paired-row
  __shared__ u16 Bs[3][8192];
  const int t = threadIdx.x, lane = t & 63, w = t >> 6;
  const int wr = w >> 2, wc = w & 3;
  const int d = blockIdx.x + gridDim.x * blockIdx.y;
  const int rr = d >> 3;
  const int m0 = ((d & 7) * 2 + (rr & 1)) * 256;
  const int n0 = (rr >> 1) * 256;
  const int li = lane & 15, lg = lane >> 4;

  const int srow = t >> 2;                       // 0..127
  const int skc  = (t & 3) ^ ((t >> 3) & 3);
  const u16* Ag = A  + (size_t)(m0 + srow) * K + skc * 8;
  const u16* Bg = Bt + (size_t)(n0 + srow) * K + skc * 8;

  auto STG_A = [&](int k0, int b) {
#pragma unroll
    for (int p = 0; p < 2; ++p)
      gl16(Ag + k0 + (size_t)(p * 128) * K, &As[b][t * 8 + p * 4096]);
  };
  auto STG_B = [&](int k0, int b) {
#pragma unroll
    for (int p = 0; p < 2; ++p)
      gl16(Bg + k0 + (size_t)(p * 128) * K, &Bs[b][t * 8 + p * 4096]);
  };

  f32x4 acc[8][4] = {};
  const int NT = K >> 5;

  STG_A(0, 0);  STG_B(0, 0);
  STG_A(32, 1); STG_B(32, 1);

  int cur = 0, nxt = 2;
  for (int kt = 0; kt < NT; ++kt) {
    if (kt + 1 < NT)
      asm volatile("s_waitcnt vmcnt(4)" ::: "memory");
    else
      asm volatile("s_waitcnt vmcnt(0)" ::: "memory");
    __builtin_amdgcn_s_barrier();
    __builtin_amdgcn_sched_barrier(0);

    const int k2 = (kt + 2) * 32;
    bf16x8 bfr[4], afA[4];
#pragma unroll
    for (int i = 0; i < 4; ++i)
      bfr[i] = *(const bf16x8*)((const char*)Bs[cur] +
                                ldsoff(wc * 64 + i * 16 + li, lg));
#pragma unroll
    for (int i = 0; i < 4; ++i)
      afA[i] = *(const bf16x8*)((const char*)As[cur] +
                                ldsoff(wr * 128 + i * 16 + li, lg));
    if (kt + 2 < NT) STG_A(k2, nxt);
    __builtin_amdgcn_s_setprio(1);
#pragma unroll
    for (int mi = 0; mi < 4; ++mi)
#pragma unroll
      for (int ni = 0; ni < 4; ++ni)
        acc[mi][ni] = __builtin_amdgcn_mfma_f32_16x16x32_bf16(
            afA[mi], bfr[ni], acc[mi][ni], 0, 0, 0);
    __builtin_amdgcn_s_setprio(0);

    bf16x8 afB[4];
#pragma unroll
    for (int i = 0; i < 4; ++i)
      afB[i] = *(const bf16x8*)((const char*)As[cur] +
                                ldsoff(wr * 128 + (4 + i) * 16 + li, lg));
    if (kt + 2 < NT) STG_B(k2, nxt);
    __builtin_amdgcn_s_setprio(1);
#pragma unroll
    for (int mi = 0; mi < 4; ++mi)
#pragma unroll
      for (int ni = 0; ni < 4; ++ni)
        acc[4 + mi][ni] = __builtin_amdgcn_mfma_f32_16x16x32_bf16(
            afB[mi], bfr[ni], acc[4 + mi][ni], 0, 0, 0);
    __builtin_amdgcn_s_setprio(0);

    cur = (cur + 1 == 3) ? 0 : cur + 1;
    nxt = (nxt + 1 == 3) ? 0 : nxt + 1;
  }

  const int crow = wr * 128 + lg * 4;
  const int ccol = wc * 64 + li;

  if (EPI == EPI_QKV) {
    const int which = n0 >> 10;                     // 0=q 1=k 2=v (uniform)
    const float* bias = which == 0 ? b0 : which == 1 ? b1 : b2;
    const int nn0 = n0 & 1023;
    if (which == 2) {
      // V: write transposed [BH][64][2048]; r -> consecutive s => u16x4 store
#pragma unroll
      for (int mi = 0; mi < 8; ++mi)
#pragma unroll
        for (int ni = 0; ni < 4; ++ni) {
          const int gm0 = m0 + crow + mi * 16;
          const int b_ = gm0 >> 11, s_ = gm0 & 2047;
          const int gc = nn0 + ccol + ni * 16;
          const int h_ = gc >> 6, d_ = gc & 63;
          u16x4 pk;
#pragma unroll
          for (int r = 0; r < 4; ++r) pk[r] = f2bfh(acc[mi][ni][r] + bias[gc]);
          *(u16x4*)(o2 + ((size_t)(b_ * 16 + h_) * 64 + d_) * 2048 + s_) = pk;
        }
    } else {
      u16* outp = which == 0 ? o0 : o1;
      const float sc = which == 0 ? QSCALE : 1.0f;
#pragma unroll
      for (int mi = 0; mi < 8; ++mi)
#pragma unroll
        for (int ni = 0; ni < 4; ++ni)
#pragma unroll
          for (int r = 0; r < 4; ++r) {
            const int gm = m0 + crow + mi * 16 + r;
            const int gc = nn0 + ccol + ni * 16;
            const float v = (acc[mi][ni][r] + bias[gc]) * sc;
            const int b_ = gm >> 11, s_ = gm & 2047;
            const int h_ = gc >> 6,  d_ = gc & 63;
            outp[((size_t)(b_ * 16 + h_) * 2048 + s_) * 64 + d_] = f2bfh(v);
          }
    }
  } else {
#pragma unroll
    for (int mi = 0; mi < 8; ++mi)
#pragma unroll
      for (int ni = 0; ni < 4; ++ni)
#pragma unroll
        for (int r = 0; r < 4; ++r) {
          const int gm = m0 + crow + mi * 16 + r;
          const int gn = n0 + ccol + ni * 16;
          const float v = acc[mi][ni][r] + b0[gn];
          const float y = 0.7978845608f * (v + 0.044715f * v * v * v);
          const float e = AEXP2(fminf(y * 2.8853900818f, 80.0f));
          const float gl = v * e * __builtin_amdgcn_rcpf(e + 1.0f);
          o0[(size_t)gm * N + gn] = f2bfh(gl);
        }
  }
}

// ---------------------------------------------------------------------------
// Skinny GEMM (Wo/FF2): BM=64 x 128, 4 waves, BK=64, 3-buffer depth-2
// pipeline with counted vmcnt(6). XCD swizzle CM=8 (XCD owns m-chunk).
// out fp32 = acc + bias + res.
// ---------------------------------------------------------------------------
template<int EPI, int BM, int CM>
__global__ __launch_bounds__(256)
void gemm_bt(const u16* __restrict__ A, const u16* __restrict__ Bt,
             const float* __restrict__ b0, const float* __restrict__ res,
             float* __restrict__ outf, u16* __restrict__ o0,
             int N, int K)
{
  constexpr int MI = BM / 32;
  constexpr int RA = BM / 32;
  static_assert(BM == 64, "vmcnt(6) assumes 6 loads/step");
  __shared__ u16 As[3][BM * 64];
  __shared__ u16 Bs[3][128 * 64];
  const int t = threadIdx.x, lane = t & 63, w = t >> 6;
  const int wr = w >> 1, wc = w & 1;
  const int d = blockIdx.x + gridDim.x * blockIdx.y;
  const int rr = d >> 3;
  const int m0 = ((d & 7) * CM + rr % CM) * BM;
  const int n0 = (rr / CM) * 128;
  const int li = lane & 15, lg = lane >> 4;

  const int srow = t >> 3;
  const int schunk = (t & 7) ^ (srow & 7);
  const u16* Ag = A  + (size_t)(m0 + srow) * K + schunk * 8;
  const u16* Bg = Bt + (size_t)(n0 + srow) * K + schunk * 8;

  auto STG = [&](int k0, int b) {
#pragma unroll
    for (int p = 0; p < RA; ++p)
      gl16(Ag + k0 + (size_t)(p * 32) * K, &As[b][t * 8 + p * 2048]);
#pragma unroll
    for (int p = 0; p < 4; ++p)
      gl16(Bg + k0 + (size_t)(p * 32) * K, &Bs[b][t * 8 + p * 2048]);
  };

  f32x4 acc[MI][4] = {};
  const int swz = (li & 7) << 4;

  auto COMPUTE = [&](int cur) {
#pragma unroll
    for (int ks = 0; ks < 2; ++ks) {
      bf16x8 af[MI], bfr[4];
#pragma unroll
      for (int i = 0; i < MI; ++i) {
        const int Ra = wr * (MI * 16) + i * 16 + li;
        af[i] = *(const bf16x8*)((const char*)As[cur] + Ra * 128 +
                                 ((ks * 64 + lg * 16) ^ swz));
      }
#pragma unroll
      for (int i = 0; i < 4; ++i) {
        const int Rb = wc * 64 + i * 16 + li;
        bfr[i] = *(const bf16x8*)((const char*)Bs[cur] + Rb * 128 +
                                  ((ks * 64 + lg * 16) ^ swz));
      }
#pragma unroll
      for (int mi = 0; mi < MI; ++mi)
#pragma unroll
        for (int ni = 0; ni < 4; ++ni)
          acc[mi][ni] = __builtin_amdgcn_mfma_f32_16x16x32_bf16(
              af[mi], bfr[ni], acc[mi][ni], 0, 0, 0);
    }
  };

  STG(0, 0);
  if (64 < K) STG(64, 1);
  int cur = 0;
  for (int k0 = 0; k0 < K; k0 += 64) {
    if (k0 + 64 < K)
      asm volatile("s_waitcnt vmcnt(6)" ::: "memory");
    else
      asm volatile("s_waitcnt vmcnt(0)" ::: "memory");
    __builtin_amdgcn_s_barrier();
    __builtin_amdgcn_sched_barrier(0);
    COMPUTE(cur);
    if (k0 + 128 < K) {
      int nxt = cur + 2; if (nxt >= 3) nxt -= 3;
      STG(k0 + 128, nxt);
    }
    cur = (cur + 1 == 3) ? 0 : cur + 1;
  }

  const int crow = wr * (MI * 16) + lg * 4;
  const int ccol = wc * 64 + li;
#pragma unroll
  for (int mi = 0; mi < MI; ++mi)
#pragma unroll
    for (int ni = 0; ni < 4; ++ni)
#pragma unroll
      for (int r = 0; r < 4; ++r) {
        const int gm = m0 + crow + mi * 16 + r;
        const int gn = n0 + ccol + ni * 16;
        const float v = acc[mi][ni][r] + b0[gn];
        const size_t o = (size_t)gm * N + gn;
        outf[o] = v + res[o];
      }
}

// ---------------------------------------------------------------------------
// Causal flash attention (r11). q prescaled by 0.125*log2e.
// ---------------------------------------------------------------------------
__global__ __launch_bounds__(512, 4)
void attn_fwd(const u16* __restrict__ qb, const u16* __restrict__ kb,
              const u16* __restrict__ vtb, u16* __restrict__ ob)
{
  __shared__ u16 Ks[2][128 * 64];
  __shared__ u16 Vt[2][64 * 128];
  __shared__ u16 Ps[8][16 * 64];
  const int t = threadIdx.x, w = t >> 6, lane = t & 63;
  const int li = lane & 15, lg = lane >> 4;
  const int bh = blockIdx.y;
  const int bx = blockIdx.x;
  const int qt = (bh & 16) ? (15 - bx) : bx;
  const int q0 = qt * 128;

  const size_t qrow = (size_t)bh * 2048 + q0 + w * 16 + li;
  const bf16x8 aq0 = *(const bf16x8*)(qb + qrow * 64 + lg * 8);
  const bf16x8 aq1 = *(const bf16x8*)(qb + qrow * 64 + lg * 8 + 32);

  f32x4 o[4] = {};
  float mrun[4], lrun[4];
#pragma unroll
  for (int r = 0; r < 4; ++r) { mrun[r] = -1e30f; lrun[r] = 0.0f; }

  const u16* kbase = kb  + (size_t)bh * 2048 * 64;
  const u16* vbase = vtb + (size_t)bh * 64 * 2048;
  const int ntile = qt + 1;

  const int kchunk = (t & 7)  ^ ((t >> 3) & 7);
  const int vchunk = (t & 15) ^ ((t >> 4) & 15);
  const u16* kg = kbase + (size_t)(t >> 3) * 64 + kchunk * 8;
  const u16* vg = vbase + (size_t)(t >> 4) * 2048 + vchunk * 8;

#define STAGE(tk_, b_)                                              \
  {                                                                 \
    const int kv0s = (tk_) * 128;                                   \
    gl16(kg + (size_t)kv0s * 64,        &Ks[b_][t * 8]);            \
    gl16(kg + (size_t)(kv0s + 64) * 64, &Ks[b_][t * 8 + 4096]);     \
    gl16(vg + kv0s,                     &Vt[b_][t * 8]);            \
    gl16(vg + kv0s + (size_t)32 * 2048, &Vt[b_][t * 8 + 4096]);     \
  }

  STAGE(0, 0);
  __syncthreads();

  for (int tk = 0; tk < ntile; ++tk) {
    const int cur = tk & 1;
    const int kv0 = tk * 128;
    if (tk + 1 < ntile) STAGE(tk + 1, 1 - cur);

    f32x4 s[8];
    __builtin_amdgcn_s_setprio(1);
#pragma unroll
    for (int cf = 0; cf < 8; ++cf) {
      const int row = cf * 16 + li;
      const char* kc = (const char*)Ks[cur] + row * 128;
      const int sw = (row & 7) << 4;
      const bf16x8 bk0 = *(const bf16x8*)(kc + ((lg * 16)      ^ sw));
      const bf16x8 bk1 = *(const bf16x8*)(kc + ((lg * 16 + 64) ^ sw));
      f32x4 z = {};
      z = __builtin_amdgcn_mfma_f32_16x16x32_bf16(aq0, bk0, z, 0, 0, 0);
      z = __builtin_amdgcn_mfma_f32_16x16x32_bf16(aq1, bk1, z, 0, 0, 0);
      s[cf] = z;
    }
    __builtin_amdgcn_s_setprio(0);
    const int row0 = q0 + w * 16 + lg * 4;
    if (tk == ntile - 1) {
#pragma unroll
      for (int cf = 0; cf < 8; ++cf)
#pragma unroll
        for (int r = 0; r < 4; ++r)
          if (kv0 + cf * 16 + li > row0 + r) s[cf][r] = -1e30f;
    }

    float pmax[4];
#pragma unroll
    for (int r = 0; r < 4; ++r) {
      const float a = fmaxf(fmaxf(s[0][r], s[1][r]), fmaxf(s[2][r], s[3][r]));
      const float b = fmaxf(fmaxf(s[4][r], s[5][r]), fmaxf(s[6][r], s[7][r]));
      pmax[r] = fmaxf(a, b);
    }
    bool need = false;
#pragma unroll
    for (int r = 0; r < 4; ++r) need = need || (pmax[r] > mrun[r] + 11.5f);
    if (__any((int)need)) {
#pragma unroll
      for (int d = 1; d < 16; d <<= 1)
#pragma unroll
        for (int r = 0; r < 4; ++r)
          pmax[r] = fmaxf(pmax[r], __shfl_xor(pmax[r], d, 64));
#pragma unroll
      for (int r = 0; r < 4; ++r) {
        const float mnew = fmaxf(mrun[r], pmax[r]);
        const float scl  = AEXP2(mrun[r] - mnew);
        lrun[r] *= scl;
#pragma unroll
        for (int n = 0; n < 4; ++n) o[n][r] *= scl;
        mrun[r] = mnew;
      }
    }
#pragma unroll
    for (int cf = 0; cf < 8; ++cf)
#pragma unroll
      for (int r = 0; r < 4; ++r) {
        const float pv = AEXP2(s[cf][r] - mrun[r]);
        s[cf][r] = pv;
        lrun[r] += pv;
      }

#pragma unroll
    for (int kh = 0; kh < 2; ++kh) {
#pragma unroll
      for (int cf2 = 0; cf2 < 4; ++cf2)
#pragma unroll
        for (int r = 0; r < 4; ++r) {
          const int prow = lg * 4 + r;
          const int pcolB = (cf2 * 16 + li) * 2;
          *(u16*)((char*)Ps[w] + prow * 128 + (pcolB ^ ((prow & 7) << 4))) =
              f2bfh(s[kh * 4 + cf2][r]);
        }
      __builtin_amdgcn_s_setprio(1);
#pragma unroll
      for (int ks = 0; ks < 2; ++ks) {
        const char* pc = (const char*)Ps[w] + li * 128;
        const bf16x8 ap =
            *(const bf16x8*)(pc + ((lg * 16 + ks * 64) ^ ((li & 7) << 4)));
#pragma unroll
        for (int n = 0; n < 4; ++n) {
          const int vrow = n * 16 + li;
          const char* vc = (const char*)Vt[cur] + vrow * 256;
          const int colB = lg * 16 + ks * 64 + kh * 128;
          const bf16x8 bv =
              *(const bf16x8*)(vc + (colB ^ ((vrow & 15) << 4)));
          o[n] = __builtin_amdgcn_mfma_f32_16x16x32_bf16(ap, bv, o[n], 0, 0, 0);
        }
      }
      __builtin_amdgcn_s_setprio(0);
    }

    __syncthreads();
  }
#undef STAGE

#pragma unroll
  for (int d = 1; d < 16; d <<= 1)
#pragma unroll
    for (int r = 0; r < 4; ++r)
      lrun[r] += __shfl_xor(lrun[r], d, 64);

  float inv[4];
#pragma unroll
  for (int r = 0; r < 4; ++r) inv[r] = __builtin_amdgcn_rcpf(lrun[r]);
  const int b_ = bh >> 4, h_ = bh & 15;
#pragma unroll
  for (int n = 0; n < 4; ++n)
#pragma unroll
    for (int r = 0; r < 4; ++r) {
      const int rowg = q0 + w * 16 + lg * 4 + r;
      ob[((size_t)b_ * 2048 + rowg) * 1024 + h_ * 64 + n * 16 + li] =
          f2bfh(o[n][r] * inv[r]);
    }
}

// ---------------------------------------------------------------------------
extern "C" void kernel_launch(void* const* d_in, const int* in_sizes, int n_in,
                              void* d_out, int out_size, void* d_ws, size_t ws_size,
                              hipStream_t stream) {
  const float* x    = (const float*)d_in[0];
  const float* ln1g = (const float*)d_in[1];
  const float* ln1b = (const float*)d_in[2];
  const float* Wq   = (const float*)d_in[3];
  const float* bq   = (const float*)d_in[4];
  const float* Wk   = (const float*)d_in[5];
  const float* bk   = (const float*)d_in[6];
  const float* Wv   = (const float*)d_in[7];
  const float* bv   = (const float*)d_in[8];
  const float* Wo   = (const float*)d_in[9];
  const float* bo   = (const float*)d_in[10];
  const float* ln2g = (const float*)d_in[11];
  const float* ln2b = (const float*)d_in[12];
  const float* W1   = (const float*)d_in[13];
  const float* b1   = (const float*)d_in[14];
  const float* W2   = (const float*)d_in[15];
  const float* b2   = (const float*)d_in[16];

  char* ws = (char*)d_ws;
  const size_t MB = 1u << 20;           // total ws use: 80 MB
  u16*   hb   = (u16*)(ws + 0);         //  8 MB  LN out bf16 [4096,1024]
  u16*   Wqt  = (u16*)(ws + 8  * MB);   //  Wq^T,Wk^T,Wv^T contiguous (6 MB)
  u16*   Wkt  = (u16*)(ws + 10 * MB);
  u16*   Wvt  = (u16*)(ws + 12 * MB);
  u16*   Wot  = (u16*)(ws + 14 * MB);   //  2 MB
  u16*   W1t  = (u16*)(ws + 16 * MB);   //  8 MB  [4096][1024]
  u16*   W2t  = (u16*)(ws + 24 * MB);   //  8 MB  [1024][4096]
  u16*   qbuf = (u16*)(ws + 32 * MB);   //  8 MB  [B,H,S,DH] (prescaled)
  u16*   kbuf = (u16*)(ws + 40 * MB);   //  8 MB  [B,H,S,DH]
  u16*   aob  = (u16*)(ws + 48 * MB);   //  8 MB  attn out [B,S,D]
  u16*   vtb  = (u16*)(ws + 56 * MB);   //  8 MB  V^T [B,H,DH,S]
  float* x2   = (float*)(ws + 64 * MB); // 16 MB  fp32 residual
  u16*   h2   = hb;                     // LN2 out reuses hb
  u16*   ff1  = qbuf;                   // 32 MB spans 32..64 (all dead by FF1)

  const dim3 blk(256);
  // transposes + LN1 in one dispatch (independent halves)
  prep_all<<<dim3(16384), blk, 0, stream>>>(Wq, Wk, Wv, Wo, W1, W2,
                                            Wqt, Wkt, Wvt, Wot, W1t, W2t,
                                            x, ln1g, ln1b, hb);

  // fused QKV: Bt = [Wq^T;Wk^T;Wv^T] rows 0..3071; V written transposed
  gemm256<EPI_QKV><<<dim3(12, 16), dim3(512), 0, stream>>>(
      hb, Wqt, bq, bk, bv, qbuf, kbuf, vtb, 3072, 1024);

  attn_fwd<<<dim3(16, 32), dim3(512), 0, stream>>>(qbuf, kbuf, vtb, aob);

  gemm_bt<EPI_RES, 64, 8><<<dim3(8, 64), blk, 0, stream>>>(
      aob, Wot, bo, x, x2, nullptr, 1024, 1024);

  ln_fwd<<<4096, blk, 0, stream>>>(x2, ln2g, ln2b, h2);

  gemm256<EPI_GELU><<<dim3(16, 16), dim3(512), 0, stream>>>(
      h2, W1t, b1, nullptr, nullptr, ff1, nullptr, nullptr, 4096, 1024);

  gemm_bt<EPI_RES, 64, 8><<<dim3(8, 64), blk, 0, stream>>>(
      ff1, W2t, b2, x2, (float*)d_out, nullptr, 1024, 4096);
}